// Round 2
// baseline (224.328 us; speedup 1.0000x reference)
//
#include <hip/hip_runtime.h>
#include <hip/hip_bf16.h>
#include <math.h>

#define BB 4
#define TT 1024
#define FF 1024
#define DIM 1024
#define NH 16
#define HD 64
#define MROWS (BB * TT)   // 4096
#define FB (FF / 64)      // 16 uint64 mask words per row

typedef __attribute__((ext_vector_type(8))) short short8;
typedef __attribute__((ext_vector_type(4))) short short4v;
typedef __attribute__((ext_vector_type(4))) float f32x4;
typedef __hip_bfloat16 bf16;

__device__ __forceinline__ void async_copy16(const void* g, void* l) {
    __builtin_amdgcn_global_load_lds((const __attribute__((address_space(1))) void*)g,
                                     (__attribute__((address_space(3))) void*)l,
                                     16, 0, 0);
}

// ---------------------------------------------------------------------------
// Fused f32->bf16 convert (segments 0..5) + mask bit-pack (tail blocks).
// ---------------------------------------------------------------------------
struct ConvArgs {
    const float* src[6];
    bf16* dst[6];
    int nvec[6];
    int blk_end[6];
    const int* mask;
    unsigned long long* Mb;
};

__global__ __launch_bounds__(256) void convert_pack(ConvArgs a) {
    int bx = blockIdx.x;
    if (bx >= a.blk_end[5]) {
        const int lane = threadIdx.x & 63;
        const int waveId = (bx - a.blk_end[5]) * 4 + (threadIdx.x >> 6);
#pragma unroll
        for (int it = 0; it < 16; ++it) {
            int c = waveId * 16 + it;
            int v = a.mask[(size_t)c * 64 + lane];
            unsigned long long bits = __ballot(v != 0);
            if (lane == 0) a.Mb[c] = bits;
        }
        return;
    }
    int seg = 0;
#pragma unroll
    for (int k = 0; k < 5; ++k) if (bx >= a.blk_end[k]) seg = k + 1;
    int b0 = seg ? a.blk_end[seg - 1] : 0;
    int idx = (bx - b0) * 256 + threadIdx.x;
    if (idx >= a.nvec[seg]) return;
    float4 v = ((const float4*)a.src[seg])[idx];
    union { bf16 t[4]; ushort4 u; } o;
    o.t[0] = __float2bfloat16(v.x);
    o.t[1] = __float2bfloat16(v.y);
    o.t[2] = __float2bfloat16(v.z);
    o.t[3] = __float2bfloat16(v.w);
    *(ushort4*)(a.dst[seg] + 4 * (size_t)idx) = o.u;
}

// ---------------------------------------------------------------------------
// Fused Q/K/Vt projection GEMMs — 256x256 tile, 8-wave, 4-quadrant-phase
// schedule with counted vmcnt. KEY FIX vs last round: barriers are
// __builtin_amdgcn_s_barrier() and waitcnts are BARE asm (no "memory"
// clobber) — a "memory"-clobber asm makes the waitcnt-insertion pass drain
// vmcnt(0) before it, killing the prefetch pipeline (measured: 59us,
// VALUBusy 8.8%). Also: phase (AH,BH) now touches EXACTLY A-half AH /
// B-half BH (row = AH*128 + wm*64 + ..., col = BH*128 + wn*32 + ...), so
// the in-buffer t+2 staging at q2/q3 provably never overlaps live reads.
//
// Pipeline invariant: at tile-t entry, outstanding loads = the 2 stages
// issued at t-1 q2/q3 (A-h0(t+1), B-h0(t+1)); vmcnt(4) at tile end
// guarantees every half staged >= 1 full tile before its first reader.
// ---------------------------------------------------------------------------
#define BK 64

struct QkvArgs {
    const bf16* A[3]; const bf16* W[3]; const float* bias[3]; bf16* C[3];
    int N[3]; int biasRow[3];
};

#define BARRIER() __builtin_amdgcn_s_barrier()
#define SCHEDB()  __builtin_amdgcn_sched_barrier(0)

__global__ __launch_bounds__(512) void gemm_qkv(QkvArgs q) {
    __shared__ bf16 lds[67584];   // 132KB: 2x64KB dbuf, epilogue 256x264

    const int op = blockIdx.y;
    const bf16* A = q.A[op];
    const bf16* W = q.W[op];
    const float* bias = q.bias[op];
    bf16* C = q.C[op];
    const int N = q.N[op];
    const int brow = q.biasRow[op];

    // XCD-compact tile map: 8 tiles per XCD cover a 2x4 (or 4x2) region.
    const int lin = blockIdx.x;
    const int xcd = lin & 7;
    const int t8  = lin >> 3;
    int mt, nt;
    if (brow) { mt = t8 & 3; nt = xcd * 2 + (t8 >> 2); }   // op2: 4M x 16N
    else      { mt = xcd * 2 + (t8 >> 2); nt = t8 & 3; }    // op0/1: 16M x 4N
    const int m0 = mt * 256, n0 = nt * 256;

    const int tid  = threadIdx.x;
    const int lane = tid & 63;
    const int wave = tid >> 6;
    const int quad = lane >> 4;
    const int l16  = lane & 15;
    const int wm   = wave >> 2;   // 0..1 -> 64-row slice within each A-half
    const int wn   = wave & 3;    // 0..3 -> 32-col slice within each B-half
    const int wbase = tid & ~63;

    // staging: thread covers row (tid>>3), swizzled 8-elem K-group
    const int srow = tid >> 3;
    const int scol = (tid & 7) ^ (srow & 7);
    const bf16* pA = A + (size_t)(m0 + srow) * DIM + scol * 8;
    const bf16* pB = W + (size_t)(n0 + srow) * DIM + scol * 8;

#define STAGE(P, ISB, TTL, HH) do { \
    const bf16* s_ = (P) + (size_t)(HH) * (128 * DIM) + (TTL) * 64; \
    bf16* d_ = lds + ((TTL) & 1) * 32768 + (ISB) * 16384 + (HH) * 8192 + wbase * 8; \
    async_copy16(s_, d_); \
    async_copy16(s_ + 64 * DIM, d_ + 4096); \
} while (0)

    f32x4 acc[8][4] = {};
    short8 a[4][2], b[4][2];

    // prologue: tile0 all 4 halves + tile1 h0 halves; leave tile1's 4 loads
    // in flight (matches steady-state invariant).
    STAGE(pA, 0, 0, 0); STAGE(pB, 1, 0, 0);
    STAGE(pA, 0, 0, 1); STAGE(pB, 1, 0, 1);
    STAGE(pA, 0, 1, 0); STAGE(pB, 1, 1, 0);
    asm volatile("s_waitcnt vmcnt(4)");
    SCHEDB();
    BARRIER();

#define LDA(AH) do { \
    _Pragma("unroll") for (int miq = 0; miq < 4; ++miq) { \
        int r_ = (AH) * 128 + wm * 64 + miq * 16 + l16; \
        const bf16* ba_ = Ab + r_ * 64; \
        a[miq][0] = *(const short8*)(ba_ + ((quad ^ (r_ & 7)) * 8)); \
        a[miq][1] = *(const short8*)(ba_ + (((quad + 4) ^ (r_ & 7)) * 8)); \
    } } while (0)

#define LDB(BH) do { \
    _Pragma("unroll") for (int niq = 0; niq < 2; ++niq) { \
        int r_ = (BH) * 128 + wn * 32 + niq * 16 + l16; \
        const bf16* bb_ = Bb + r_ * 64; \
        b[(BH) * 2 + niq][0] = *(const short8*)(bb_ + ((quad ^ (r_ & 7)) * 8)); \
        b[(BH) * 2 + niq][1] = *(const short8*)(bb_ + (((quad + 4) ^ (r_ & 7)) * 8)); \
    } } while (0)

#define MMA(AH, BH) do { \
    _Pragma("unroll") for (int miq = 0; miq < 4; ++miq) \
    _Pragma("unroll") for (int niq = 0; niq < 2; ++niq) { \
        f32x4& c_ = acc[(AH) * 4 + miq][(BH) * 2 + niq]; \
        c_ = __builtin_amdgcn_mfma_f32_16x16x32_bf16(a[miq][0], b[(BH) * 2 + niq][0], c_, 0, 0, 0); \
        c_ = __builtin_amdgcn_mfma_f32_16x16x32_bf16(a[miq][1], b[(BH) * 2 + niq][1], c_, 0, 0, 0); \
    } } while (0)

#define PHASE_MFMA(AH, BH) do { \
    BARRIER(); SCHEDB(); \
    __builtin_amdgcn_s_setprio(1); \
    MMA(AH, BH); \
    __builtin_amdgcn_s_setprio(0); \
    SCHEDB(); \
} while (0)

#pragma unroll 2
    for (int t = 0; t < 16; ++t) {
        const bf16* Ab = lds + (t & 1) * 32768;
        const bf16* Bb = Ab + 16384;

        // q0: quadrant (A-h0, B-h0); 12 ds_reads
        LDA(0); LDB(0);
        if (t + 1 < 16) STAGE(pA, 0, t + 1, 1);
        PHASE_MFMA(0, 0);
        BARRIER();

        // q1: quadrant (A-h0, B-h1); 4 ds_reads (b[2..3] held for q3)
        LDB(1);
        if (t + 1 < 16) STAGE(pB, 1, t + 1, 1);
        PHASE_MFMA(0, 1);
        BARRIER();

        // q2: quadrant (A-h1, B-h0); 8 ds_reads. A-h0 reads fully done ->
        // safe to overwrite current buffer's A-h0 region with tile t+2.
        LDA(1);
        if (t + 2 < 16) STAGE(pA, 0, t + 2, 0);
        PHASE_MFMA(1, 0);
        BARRIER();

        // q3: quadrant (A-h1, B-h1); 0 ds_reads; counted vmcnt once/tile
        if (t + 2 < 16) STAGE(pB, 1, t + 2, 0);
        PHASE_MFMA(1, 1);
        if (t < 14)       { asm volatile("s_waitcnt vmcnt(4)"); }
        else if (t == 14) { asm volatile("s_waitcnt vmcnt(0)"); }
        SCHEDB();
        BARRIER();
    }

    // epilogue: bias + bf16 convert into LDS tile, then coalesced 16B stores
    bf16* Cs = lds;
#pragma unroll
    for (int ni = 0; ni < 4; ++ni) {
        const int nl = (ni >> 1) * 128 + wn * 32 + (ni & 1) * 16 + l16;
        float bcol = brow ? 0.0f : bias[n0 + nl];
#pragma unroll
        for (int mi = 0; mi < 8; ++mi)
#pragma unroll
            for (int i = 0; i < 4; ++i) {
                const int ml = (mi >> 2) * 128 + wm * 64 + (mi & 3) * 16 + quad * 4 + i;
                float v = acc[mi][ni][i] + (brow ? bias[m0 + ml] : bcol);
                Cs[ml * 264 + nl] = __float2bfloat16(v);
            }
    }
    __syncthreads();
#pragma unroll
    for (int j = 0; j < 16; ++j) {
        int slot = j * 512 + tid;
        int rr = slot >> 5, cc = slot & 31;
        short8 v = *(const short8*)(Cs + rr * 264 + cc * 8);
        *(short8*)(C + (size_t)(m0 + rr) * N + n0 + cc * 8) = v;
    }
#undef STAGE
#undef LDA
#undef LDB
#undef MMA
#undef PHASE_MFMA
}

// ---------------------------------------------------------------------------
// O-projection GEMM (unchanged).
// ---------------------------------------------------------------------------
__global__ __launch_bounds__(256) void gemm_o(
    const bf16* __restrict__ A, const bf16* __restrict__ W,
    const float* __restrict__ bias, float* __restrict__ C)
{
    __shared__ float smemf[128 * 66];
    bf16* As = (bf16*)smemf;
    bf16* Bs = As + 128 * BK;

    const int lin = blockIdx.x + 16 * blockIdx.y;
    const int xcd = lin & 7;
    const int t   = lin >> 3;
    const int m0 = (xcd * 4 + (t >> 4)) * 128;
    const int n0 = (((t & 15) + 2 * xcd) & 15) * 64;

    const int tid  = threadIdx.x;
    const int lane = tid & 63;
    const int wave = tid >> 6;
    const int quad = lane >> 4;
    const int l16  = lane & 15;
    const int wm = wave & 1;
    const int wn = wave >> 1;
    const int wbase = tid & ~63;

    f32x4 acc[4][2] = {};

    for (int k0 = 0; k0 < DIM; k0 += BK) {
#pragma unroll
        for (int j = 0; j < 4; ++j) {
            int slot = j * 256 + tid;
            int r = slot >> 3;
            int g = (slot & 7) ^ (r & 7);
            async_copy16(A + (size_t)(m0 + r) * DIM + k0 + g * 8,
                         As + (size_t)(j * 256 + wbase) * 8);
        }
#pragma unroll
        for (int j = 0; j < 2; ++j) {
            int slot = j * 256 + tid;
            int r = slot >> 3;
            int g = (slot & 7) ^ (r & 7);
            async_copy16(W + (size_t)(n0 + r) * DIM + k0 + g * 8,
                         Bs + (size_t)(j * 256 + wbase) * 8);
        }
        __syncthreads();

#pragma unroll
        for (int kk = 0; kk < 2; ++kk) {
            short8 a[4], b[2];
#pragma unroll
            for (int mi = 0; mi < 4; ++mi) {
                int r = wm * 64 + mi * 16 + l16;
                int p = (kk * 4 + quad) ^ (r & 7);
                a[mi] = *(const short8*)(As + r * BK + p * 8);
            }
#pragma unroll
            for (int ni = 0; ni < 2; ++ni) {
                int r = wn * 32 + ni * 16 + l16;
                int p = (kk * 4 + quad) ^ (r & 7);
                b[ni] = *(const short8*)(Bs + r * BK + p * 8);
            }
#pragma unroll
            for (int mi = 0; mi < 4; ++mi)
#pragma unroll
                for (int ni = 0; ni < 2; ++ni)
                    acc[mi][ni] = __builtin_amdgcn_mfma_f32_16x16x32_bf16(
                        a[mi], b[ni], acc[mi][ni], 0, 0, 0);
        }
        __syncthreads();
    }

    float* Cs = smemf;
#pragma unroll
    for (int ni = 0; ni < 2; ++ni) {
        const int nl = wn * 32 + ni * 16 + l16;
        const float bcol = bias[n0 + nl];
#pragma unroll
        for (int mi = 0; mi < 4; ++mi)
#pragma unroll
            for (int i = 0; i < 4; ++i) {
                const int ml = wm * 64 + mi * 16 + quad * 4 + i;
                Cs[ml * 66 + nl] = acc[mi][ni][i] + bcol;
            }
    }
    __syncthreads();
#pragma unroll
    for (int j = 0; j < 8; ++j) {
        int slot = j * 256 + tid;
        int rr = slot >> 4, cc = slot & 15;
        float4 v = *(const float4*)(Cs + rr * 66 + cc * 4);
        *(float4*)(C + (size_t)(m0 + rr) * DIM + n0 + cc * 4) = v;
    }
}

// ---------------------------------------------------------------------------
// MFMA flash attention, S^T formulation (unchanged).
// ---------------------------------------------------------------------------
__global__ __launch_bounds__(256, 4) void attn_kernel(
    const bf16* Qg, const bf16* __restrict__ Kg, const bf16* __restrict__ Vtg,
    const unsigned long long* __restrict__ Mbits, bf16* Og)
{
    __shared__ bf16 Ks[128 * 64];    // [f][d], 8-chunk XOR swizzle
    __shared__ bf16 Vts[64 * 128];   // [d][f], 16-chunk XOR swizzle
    __shared__ bf16 Pt[64 * 136];    // [t][f], padded rows
    __shared__ float ls[64];         // l transpose

    const int tid  = threadIdx.x;
    const int lane = tid & 63;
    const int wave = tid >> 6;
    const int quad = lane >> 4;
    const int l16  = lane & 15;

    const int lin = blockIdx.x + 16 * (blockIdx.y + 16 * blockIdx.z);
    const int xcd = lin & 7;
    const int t   = lin >> 3;
    const int bh  = xcd * 8 + (t >> 4);
    const int b   = bh >> 4;
    const int h   = bh & 15;
    const int t0  = (t & 15) * 64;

    const size_t qrow0 = (size_t)b * TT + t0;
    const size_t krow0 = (size_t)b * FF;
    const int wbase = tid & ~63;
    const int myrow = wave * 16 + l16;   // this lane's t-row

    // Q fragments (B-operand: n=t=l16, k=d) direct from global
    const bf16* qptr = Qg + (qrow0 + myrow) * DIM + h * HD;
    short8 qb0 = *(const short8*)(qptr + quad * 8);
    short8 qb1 = *(const short8*)(qptr + 32 + quad * 8);

    // mask: this lane's row, 2 words per iteration, software prefetch
    const unsigned long long* mrow = Mbits + (qrow0 + myrow) * FB;
    unsigned long long w0 = mrow[0];
    unsigned long long w1 = mrow[1];

    float lsum = 0.f;
    f32x4 oacc[4] = {};

#pragma unroll 1
    for (int it = 0; it < 8; ++it) {
        const int f0 = it * 128;
        // stage K chunk 128x64 and Vt chunk 64x128
#pragma unroll
        for (int j = 0; j < 4; ++j) {
            int slot = j * 256 + tid;
            int rk = slot >> 3;
            int gk = (slot & 7) ^ (rk & 7);
            async_copy16(Kg + (krow0 + f0 + rk) * DIM + h * HD + gk * 8,
                         Ks + (size_t)(j * 256 + wbase) * 8);
            int rv = slot >> 4;
            int gv = (slot & 15) ^ (rv & 15);
            async_copy16(Vtg + (size_t)(h * HD + rv) * MROWS + b * FF + f0 + gv * 8,
                         Vts + (size_t)(j * 256 + wbase) * 8);
        }
        // prefetch next iteration's mask words (hidden behind this iter)
        unsigned long long nw0 = 0, nw1 = 0;
        if (it < 7) { nw0 = mrow[2 * it + 2]; nw1 = mrow[2 * it + 3]; }
        __syncthreads();

        // S^T = K @ Q^T : 128 f-rows x 16 t-cols per wave (A=K, B=Q)
        f32x4 sacc[8];
#pragma unroll
        for (int ft = 0; ft < 8; ++ft) {
            int r = ft * 16 + l16;
            short8 ka0 = *(const short8*)(Ks + r * 64 + ((quad       ^ (r & 7)) * 8));
            short8 ka1 = *(const short8*)(Ks + r * 64 + (((quad + 4) ^ (r & 7)) * 8));
            f32x4 s = {};
            s = __builtin_amdgcn_mfma_f32_16x16x32_bf16(ka0, qb0, s, 0, 0, 0);
            s = __builtin_amdgcn_mfma_f32_16x16x32_bf16(ka1, qb1, s, 0, 0, 0);
            sacc[ft] = s;
        }

        // exp + mask + vectorized P writes (lane: t=myrow, f=ft*16+quad*4+i)
#pragma unroll
        for (int ft = 0; ft < 8; ++ft) {
            const unsigned long long word = (ft < 4) ? w0 : w1;
            const unsigned bits4 =
                (unsigned)(word >> ((ft & 3) * 16 + quad * 4)) & 0xFu;
            union { short4v v; short s[4]; } pk;
            float psum = 0.f;
#pragma unroll
            for (int i = 0; i < 4; ++i) {
                float p = (bits4 >> i) & 1u ? __expf(sacc[ft][i] * 0.125f) : 0.f;
                psum += p;
                pk.s[i] = (short)__bfloat16_as_ushort(__float2bfloat16(p));
            }
            lsum += psum;
            *(short4v*)(Pt + myrow * 136 + ft * 16 + quad * 4) = pk.v;
        }
        w0 = nw0; w1 = nw1;

        // PV A-frags from own Pt rows (in-order same-wave LDS)
        short8 pa[4];
#pragma unroll
        for (int kf = 0; kf < 4; ++kf)
            pa[kf] = *(const short8*)(Pt + myrow * 136 + kf * 32 + quad * 8);
#pragma unroll
        for (int nt = 0; nt < 4; ++nt) {
            int rd = nt * 16 + l16;
#pragma unroll
            for (int kf = 0; kf < 4; ++kf) {
                int g = (kf * 4 + quad) ^ (rd & 15);
                short8 vb = *(const short8*)(Vts + rd * 128 + g * 8);
                oacc[nt] = __builtin_amdgcn_mfma_f32_16x16x32_bf16(pa[kf], vb, oacc[nt], 0, 0, 0);
            }
        }
        __syncthreads();   // protect Ks/Vts before next staging
    }

    // reduce l across quads (lanes sharing l16)
    lsum += __shfl_xor(lsum, 16);
    lsum += __shfl_xor(lsum, 32);
    if (quad == 0) ls[myrow] = lsum;   // same-wave readback below

    // epilogue: normalize (l for t=quad*4+i via ls) + coalesced store via Pt
#pragma unroll
    for (int i = 0; i < 4; ++i) {
        float inv = 1.0f / ls[wave * 16 + quad * 4 + i];
        const int prow = wave * 16 + quad * 4 + i;
#pragma unroll
        for (int nt = 0; nt < 4; ++nt)
            Pt[prow * 136 + nt * 16 + l16] = __float2bfloat16(oacc[nt][i] * inv);
    }
    __syncthreads();
#pragma unroll
    for (int j = 0; j < 2; ++j) {
        int s = j * 256 + tid;
        int rr = s >> 3, off = (s & 7) * 8;
        short8 v = *(const short8*)(Pt + rr * 136 + off);
        *(short8*)(Og + (qrow0 + rr) * DIM + h * HD + off) = v;
    }
}

// ---------------------------------------------------------------------------
extern "C" void kernel_launch(void* const* d_in, const int* in_sizes, int n_in,
                              void* d_out, int out_size, void* d_ws, size_t ws_size,
                              hipStream_t stream) {
    const float* X_to   = (const float*)d_in[0];
    const float* X_from = (const float*)d_in[1];
    const int*   mask   = (const int*)  d_in[2];
    const float* Wq     = (const float*)d_in[3];
    const float* bq     = (const float*)d_in[4];
    const float* Wk     = (const float*)d_in[5];
    const float* bk     = (const float*)d_in[6];
    const float* Wv     = (const float*)d_in[7];
    const float* bv     = (const float*)d_in[8];
    const float* Wo     = (const float*)d_in[9];
    const float* bo     = (const float*)d_in[10];
    float* out = (float*)d_out;

    char* ws = (char*)d_ws;
    bf16* Xt16 = (bf16*)(ws);
    bf16* Xf16 = (bf16*)(ws + (8u  << 20));
    bf16* Wq16 = (bf16*)(ws + (16u << 20));
    bf16* Wv16 = (bf16*)(ws + (18u << 20));
    bf16* Wk16 = (bf16*)(ws + (20u << 20));
    bf16* Wo16 = (bf16*)(ws + (22u << 20));
    bf16* Q16  = (bf16*)(ws + (24u << 20));
    bf16* K16  = (bf16*)(ws + (32u << 20));
    bf16* Vt16 = (bf16*)(ws + (40u << 20));
    unsigned long long* Mb = (unsigned long long*)(ws + (48u << 20));

    ConvArgs ca;
    ca.src[0] = X_to;   ca.dst[0] = Xt16; ca.nvec[0] = MROWS * DIM / 4;
    ca.src[1] = X_from; ca.dst[1] = Xf16; ca.nvec[1] = MROWS * DIM / 4;
    ca.src[2] = Wq;     ca.dst[2] = Wq16; ca.nvec[2] = DIM * DIM / 4;
    ca.src[3] = Wv;     ca.dst[3] = Wv16; ca.nvec[3] = DIM * DIM / 4;
    ca.src[4] = Wk;     ca.dst[4] = Wk16; ca.nvec[4] = DIM * DIM / 4;
    ca.src[5] = Wo;     ca.dst[5] = Wo16; ca.nvec[5] = DIM * DIM / 4;
    int cum = 0;
    for (int k = 0; k < 6; ++k) { cum += ca.nvec[k] / 256; ca.blk_end[k] = cum; }
    ca.mask = mask; ca.Mb = Mb;
    convert_pack<<<cum + 1024, 256, 0, stream>>>(ca);

    QkvArgs qa;
    qa.A[0] = Xt16; qa.W[0] = Wq16; qa.bias[0] = bq; qa.C[0] = Q16;
    qa.N[0] = DIM; qa.biasRow[0] = 0;
    qa.A[1] = Xf16; qa.W[1] = Wv16; qa.bias[1] = bv; qa.C[1] = K16;
    qa.N[1] = DIM; qa.biasRow[1] = 0;
    qa.A[2] = Wk16; qa.W[2] = Xf16; qa.bias[2] = bk; qa.C[2] = Vt16;
    qa.N[2] = MROWS; qa.biasRow[2] = 1;
    gemm_qkv<<<dim3(64, 3), 512, 0, stream>>>(qa);

    attn_kernel<<<dim3(TT / 64, NH, BB), 256, 0, stream>>>(
        Q16, K16, Vt16, Mb, Q16);

    gemm_o<<<dim3(DIM / 64, MROWS / 128), 256, 0, stream>>>(Q16, Wo16, bo, out);
}

// Round 3
// 223.484 us; speedup vs baseline: 1.0038x; 1.0038x over previous
//
#include <hip/hip_runtime.h>
#include <hip/hip_bf16.h>
#include <math.h>

#define BB 4
#define TT 1024
#define FF 1024
#define DIM 1024
#define NH 16
#define HD 64
#define MROWS (BB * TT)   // 4096
#define FB (FF / 64)      // 16 uint64 mask words per row

typedef __attribute__((ext_vector_type(8))) short short8;
typedef __attribute__((ext_vector_type(4))) short short4v;
typedef __attribute__((ext_vector_type(4))) float f32x4;
typedef __hip_bfloat16 bf16;

__device__ __forceinline__ void async_copy16(const void* g, void* l) {
    __builtin_amdgcn_global_load_lds((const __attribute__((address_space(1))) void*)g,
                                     (__attribute__((address_space(3))) void*)l,
                                     16, 0, 0);
}

// ---------------------------------------------------------------------------
// Fused f32->bf16 convert (segments 0..5) + mask bit-pack (tail blocks).
// ---------------------------------------------------------------------------
struct ConvArgs {
    const float* src[6];
    bf16* dst[6];
    int nvec[6];
    int blk_end[6];
    const int* mask;
    unsigned long long* Mb;
};

__global__ __launch_bounds__(256) void convert_pack(ConvArgs a) {
    int bx = blockIdx.x;
    if (bx >= a.blk_end[5]) {
        const int lane = threadIdx.x & 63;
        const int waveId = (bx - a.blk_end[5]) * 4 + (threadIdx.x >> 6);
#pragma unroll
        for (int it = 0; it < 16; ++it) {
            int c = waveId * 16 + it;
            int v = a.mask[(size_t)c * 64 + lane];
            unsigned long long bits = __ballot(v != 0);
            if (lane == 0) a.Mb[c] = bits;
        }
        return;
    }
    int seg = 0;
#pragma unroll
    for (int k = 0; k < 5; ++k) if (bx >= a.blk_end[k]) seg = k + 1;
    int b0 = seg ? a.blk_end[seg - 1] : 0;
    int idx = (bx - b0) * 256 + threadIdx.x;
    if (idx >= a.nvec[seg]) return;
    float4 v = ((const float4*)a.src[seg])[idx];
    union { bf16 t[4]; ushort4 u; } o;
    o.t[0] = __float2bfloat16(v.x);
    o.t[1] = __float2bfloat16(v.y);
    o.t[2] = __float2bfloat16(v.z);
    o.t[3] = __float2bfloat16(v.w);
    *(ushort4*)(a.dst[seg] + 4 * (size_t)idx) = o.u;
}

// ---------------------------------------------------------------------------
// Fused Q/K/Vt projection GEMMs — 256x256 tile, 8-wave, 4-quadrant-phase
// schedule with counted vmcnt (m201 template form). KEY FIX vs round 2:
// NO sched_barrier(0) anywhere in the main loop — m141 measured that
// sched_barrier(0) order-pinning costs ~40% (510 vs 874 TF) by defeating
// the compiler's own fine-grained waitcnt scheduling; the m201 template's
// main loop contains none. Barriers are builtin s_barrier (no drain);
// waits are bare counted vmcnt asm, each immediately followed by a
// barrier so no dependent LDS op can be hoisted above them.
//
// Pipeline invariant: at tile-t entry, outstanding loads = the 2 stages
// issued at t-1 q2/q3 (A-h0(t+1), B-h0(t+1)); vmcnt(4) at tile end
// guarantees every half staged >= 1 full tile before its first reader.
// Phase (AH,BH) touches exactly A-half AH / B-half BH, so the in-buffer
// t+2 staging at q2/q3 never overlaps live reads.
// ---------------------------------------------------------------------------
#define BK 64

struct QkvArgs {
    const bf16* A[3]; const bf16* W[3]; const float* bias[3]; bf16* C[3];
    int N[3]; int biasRow[3];
};

#define BARRIER() __builtin_amdgcn_s_barrier()

__global__ __launch_bounds__(512) void gemm_qkv(QkvArgs q) {
    __shared__ bf16 lds[67584];   // 132KB: 2x64KB dbuf, epilogue 256x264

    const int op = blockIdx.y;
    const bf16* A = q.A[op];
    const bf16* W = q.W[op];
    const float* bias = q.bias[op];
    bf16* C = q.C[op];
    const int N = q.N[op];
    const int brow = q.biasRow[op];

    // XCD-compact tile map: 8 tiles per XCD cover a 2x4 (or 4x2) region.
    const int lin = blockIdx.x;
    const int xcd = lin & 7;
    const int t8  = lin >> 3;
    int mt, nt;
    if (brow) { mt = t8 & 3; nt = xcd * 2 + (t8 >> 2); }   // op2: 4M x 16N
    else      { mt = xcd * 2 + (t8 >> 2); nt = t8 & 3; }    // op0/1: 16M x 4N
    const int m0 = mt * 256, n0 = nt * 256;

    const int tid  = threadIdx.x;
    const int lane = tid & 63;
    const int wave = tid >> 6;
    const int quad = lane >> 4;
    const int l16  = lane & 15;
    const int wm   = wave >> 2;   // 0..1 -> 64-row slice within each A-half
    const int wn   = wave & 3;    // 0..3 -> 32-col slice within each B-half
    const int wbase = tid & ~63;

    // staging: thread covers row (tid>>3), swizzled 8-elem K-group
    const int srow = tid >> 3;
    const int scol = (tid & 7) ^ (srow & 7);
    const bf16* pA = A + (size_t)(m0 + srow) * DIM + scol * 8;
    const bf16* pB = W + (size_t)(n0 + srow) * DIM + scol * 8;

#define STAGE(P, ISB, TTL, HH) do { \
    const bf16* s_ = (P) + (size_t)(HH) * (128 * DIM) + (TTL) * 64; \
    bf16* d_ = lds + ((TTL) & 1) * 32768 + (ISB) * 16384 + (HH) * 8192 + wbase * 8; \
    async_copy16(s_, d_); \
    async_copy16(s_ + 64 * DIM, d_ + 4096); \
} while (0)

    f32x4 acc[8][4] = {};
    short8 a[4][2], b[4][2];

    // prologue: tile0 all 4 halves + tile1 h0 halves; leave tile1's 4 loads
    // in flight (matches steady-state invariant).
    STAGE(pA, 0, 0, 0); STAGE(pB, 1, 0, 0);
    STAGE(pA, 0, 0, 1); STAGE(pB, 1, 0, 1);
    STAGE(pA, 0, 1, 0); STAGE(pB, 1, 1, 0);
    asm volatile("s_waitcnt vmcnt(4)");
    BARRIER();

#define LDA(AH) do { \
    _Pragma("unroll") for (int miq = 0; miq < 4; ++miq) { \
        int r_ = (AH) * 128 + wm * 64 + miq * 16 + l16; \
        const bf16* ba_ = Ab + r_ * 64; \
        a[miq][0] = *(const short8*)(ba_ + ((quad ^ (r_ & 7)) * 8)); \
        a[miq][1] = *(const short8*)(ba_ + (((quad + 4) ^ (r_ & 7)) * 8)); \
    } } while (0)

#define LDB(BH) do { \
    _Pragma("unroll") for (int niq = 0; niq < 2; ++niq) { \
        int r_ = (BH) * 128 + wn * 32 + niq * 16 + l16; \
        const bf16* bb_ = Bb + r_ * 64; \
        b[(BH) * 2 + niq][0] = *(const short8*)(bb_ + ((quad ^ (r_ & 7)) * 8)); \
        b[(BH) * 2 + niq][1] = *(const short8*)(bb_ + (((quad + 4) ^ (r_ & 7)) * 8)); \
    } } while (0)

#define MMA(AH, BH) do { \
    _Pragma("unroll") for (int miq = 0; miq < 4; ++miq) \
    _Pragma("unroll") for (int niq = 0; niq < 2; ++niq) { \
        f32x4& c_ = acc[(AH) * 4 + miq][(BH) * 2 + niq]; \
        c_ = __builtin_amdgcn_mfma_f32_16x16x32_bf16(a[miq][0], b[(BH) * 2 + niq][0], c_, 0, 0, 0); \
        c_ = __builtin_amdgcn_mfma_f32_16x16x32_bf16(a[miq][1], b[(BH) * 2 + niq][1], c_, 0, 0, 0); \
    } } while (0)

#define PHASE_MFMA(AH, BH) do { \
    BARRIER(); \
    __builtin_amdgcn_s_setprio(1); \
    MMA(AH, BH); \
    __builtin_amdgcn_s_setprio(0); \
} while (0)

#pragma unroll 2
    for (int t = 0; t < 16; ++t) {
        const bf16* Ab = lds + (t & 1) * 32768;
        const bf16* Bb = Ab + 16384;

        // q0: quadrant (A-h0, B-h0); 12 ds_reads
        LDA(0); LDB(0);
        if (t + 1 < 16) STAGE(pA, 0, t + 1, 1);
        PHASE_MFMA(0, 0);
        BARRIER();

        // q1: quadrant (A-h0, B-h1); 4 ds_reads (b[2..3] held for q3)
        LDB(1);
        if (t + 1 < 16) STAGE(pB, 1, t + 1, 1);
        PHASE_MFMA(0, 1);
        BARRIER();

        // q2: quadrant (A-h1, B-h0); 8 ds_reads. A-h0 reads fully done ->
        // safe to overwrite current buffer's A-h0 region with tile t+2.
        LDA(1);
        if (t + 2 < 16) STAGE(pA, 0, t + 2, 0);
        PHASE_MFMA(1, 0);
        BARRIER();

        // q3: quadrant (A-h1, B-h1); 0 ds_reads; counted vmcnt once/tile
        if (t + 2 < 16) STAGE(pB, 1, t + 2, 0);
        PHASE_MFMA(1, 1);
        if (t < 14)       { asm volatile("s_waitcnt vmcnt(4)"); }
        else if (t == 14) { asm volatile("s_waitcnt vmcnt(0)"); }
        BARRIER();
    }

    // epilogue: bias + bf16 convert into LDS tile, then coalesced 16B stores
    bf16* Cs = lds;
#pragma unroll
    for (int ni = 0; ni < 4; ++ni) {
        const int nl = (ni >> 1) * 128 + wn * 32 + (ni & 1) * 16 + l16;
        float bcol = brow ? 0.0f : bias[n0 + nl];
#pragma unroll
        for (int mi = 0; mi < 8; ++mi)
#pragma unroll
            for (int i = 0; i < 4; ++i) {
                const int ml = (mi >> 2) * 128 + wm * 64 + (mi & 3) * 16 + quad * 4 + i;
                float v = acc[mi][ni][i] + (brow ? bias[m0 + ml] : bcol);
                Cs[ml * 264 + nl] = __float2bfloat16(v);
            }
    }
    __syncthreads();
#pragma unroll
    for (int j = 0; j < 16; ++j) {
        int slot = j * 512 + tid;
        int rr = slot >> 5, cc = slot & 31;
        short8 v = *(const short8*)(Cs + rr * 264 + cc * 8);
        *(short8*)(C + (size_t)(m0 + rr) * N + n0 + cc * 8) = v;
    }
#undef STAGE
#undef LDA
#undef LDB
#undef MMA
#undef PHASE_MFMA
}

// ---------------------------------------------------------------------------
// O-projection GEMM (unchanged).
// ---------------------------------------------------------------------------
__global__ __launch_bounds__(256) void gemm_o(
    const bf16* __restrict__ A, const bf16* __restrict__ W,
    const float* __restrict__ bias, float* __restrict__ C)
{
    __shared__ float smemf[128 * 66];
    bf16* As = (bf16*)smemf;
    bf16* Bs = As + 128 * BK;

    const int lin = blockIdx.x + 16 * blockIdx.y;
    const int xcd = lin & 7;
    const int t   = lin >> 3;
    const int m0 = (xcd * 4 + (t >> 4)) * 128;
    const int n0 = (((t & 15) + 2 * xcd) & 15) * 64;

    const int tid  = threadIdx.x;
    const int lane = tid & 63;
    const int wave = tid >> 6;
    const int quad = lane >> 4;
    const int l16  = lane & 15;
    const int wm = wave & 1;
    const int wn = wave >> 1;
    const int wbase = tid & ~63;

    f32x4 acc[4][2] = {};

    for (int k0 = 0; k0 < DIM; k0 += BK) {
#pragma unroll
        for (int j = 0; j < 4; ++j) {
            int slot = j * 256 + tid;
            int r = slot >> 3;
            int g = (slot & 7) ^ (r & 7);
            async_copy16(A + (size_t)(m0 + r) * DIM + k0 + g * 8,
                         As + (size_t)(j * 256 + wbase) * 8);
        }
#pragma unroll
        for (int j = 0; j < 2; ++j) {
            int slot = j * 256 + tid;
            int r = slot >> 3;
            int g = (slot & 7) ^ (r & 7);
            async_copy16(W + (size_t)(n0 + r) * DIM + k0 + g * 8,
                         Bs + (size_t)(j * 256 + wbase) * 8);
        }
        __syncthreads();

#pragma unroll
        for (int kk = 0; kk < 2; ++kk) {
            short8 a[4], b[2];
#pragma unroll
            for (int mi = 0; mi < 4; ++mi) {
                int r = wm * 64 + mi * 16 + l16;
                int p = (kk * 4 + quad) ^ (r & 7);
                a[mi] = *(const short8*)(As + r * BK + p * 8);
            }
#pragma unroll
            for (int ni = 0; ni < 2; ++ni) {
                int r = wn * 32 + ni * 16 + l16;
                int p = (kk * 4 + quad) ^ (r & 7);
                b[ni] = *(const short8*)(Bs + r * BK + p * 8);
            }
#pragma unroll
            for (int mi = 0; mi < 4; ++mi)
#pragma unroll
                for (int ni = 0; ni < 2; ++ni)
                    acc[mi][ni] = __builtin_amdgcn_mfma_f32_16x16x32_bf16(
                        a[mi], b[ni], acc[mi][ni], 0, 0, 0);
        }
        __syncthreads();
    }

    float* Cs = smemf;
#pragma unroll
    for (int ni = 0; ni < 2; ++ni) {
        const int nl = wn * 32 + ni * 16 + l16;
        const float bcol = bias[n0 + nl];
#pragma unroll
        for (int mi = 0; mi < 4; ++mi)
#pragma unroll
            for (int i = 0; i < 4; ++i) {
                const int ml = wm * 64 + mi * 16 + quad * 4 + i;
                Cs[ml * 66 + nl] = acc[mi][ni][i] + bcol;
            }
    }
    __syncthreads();
#pragma unroll
    for (int j = 0; j < 8; ++j) {
        int slot = j * 256 + tid;
        int rr = slot >> 4, cc = slot & 15;
        float4 v = *(const float4*)(Cs + rr * 66 + cc * 4);
        *(float4*)(C + (size_t)(m0 + rr) * DIM + n0 + cc * 4) = v;
    }
}

// ---------------------------------------------------------------------------
// MFMA flash attention, S^T formulation (unchanged).
// ---------------------------------------------------------------------------
__global__ __launch_bounds__(256, 4) void attn_kernel(
    const bf16* Qg, const bf16* __restrict__ Kg, const bf16* __restrict__ Vtg,
    const unsigned long long* __restrict__ Mbits, bf16* Og)
{
    __shared__ bf16 Ks[128 * 64];    // [f][d], 8-chunk XOR swizzle
    __shared__ bf16 Vts[64 * 128];   // [d][f], 16-chunk XOR swizzle
    __shared__ bf16 Pt[64 * 136];    // [t][f], padded rows
    __shared__ float ls[64];         // l transpose

    const int tid  = threadIdx.x;
    const int lane = tid & 63;
    const int wave = tid >> 6;
    const int quad = lane >> 4;
    const int l16  = lane & 15;

    const int lin = blockIdx.x + 16 * (blockIdx.y + 16 * blockIdx.z);
    const int xcd = lin & 7;
    const int t   = lin >> 3;
    const int bh  = xcd * 8 + (t >> 4);
    const int b   = bh >> 4;
    const int h   = bh & 15;
    const int t0  = (t & 15) * 64;

    const size_t qrow0 = (size_t)b * TT + t0;
    const size_t krow0 = (size_t)b * FF;
    const int wbase = tid & ~63;
    const int myrow = wave * 16 + l16;   // this lane's t-row

    // Q fragments (B-operand: n=t=l16, k=d) direct from global
    const bf16* qptr = Qg + (qrow0 + myrow) * DIM + h * HD;
    short8 qb0 = *(const short8*)(qptr + quad * 8);
    short8 qb1 = *(const short8*)(qptr + 32 + quad * 8);

    // mask: this lane's row, 2 words per iteration, software prefetch
    const unsigned long long* mrow = Mbits + (qrow0 + myrow) * FB;
    unsigned long long w0 = mrow[0];
    unsigned long long w1 = mrow[1];

    float lsum = 0.f;
    f32x4 oacc[4] = {};

#pragma unroll 1
    for (int it = 0; it < 8; ++it) {
        const int f0 = it * 128;
        // stage K chunk 128x64 and Vt chunk 64x128
#pragma unroll
        for (int j = 0; j < 4; ++j) {
            int slot = j * 256 + tid;
            int rk = slot >> 3;
            int gk = (slot & 7) ^ (rk & 7);
            async_copy16(Kg + (krow0 + f0 + rk) * DIM + h * HD + gk * 8,
                         Ks + (size_t)(j * 256 + wbase) * 8);
            int rv = slot >> 4;
            int gv = (slot & 15) ^ (rv & 15);
            async_copy16(Vtg + (size_t)(h * HD + rv) * MROWS + b * FF + f0 + gv * 8,
                         Vts + (size_t)(j * 256 + wbase) * 8);
        }
        // prefetch next iteration's mask words (hidden behind this iter)
        unsigned long long nw0 = 0, nw1 = 0;
        if (it < 7) { nw0 = mrow[2 * it + 2]; nw1 = mrow[2 * it + 3]; }
        __syncthreads();

        // S^T = K @ Q^T : 128 f-rows x 16 t-cols per wave (A=K, B=Q)
        f32x4 sacc[8];
#pragma unroll
        for (int ft = 0; ft < 8; ++ft) {
            int r = ft * 16 + l16;
            short8 ka0 = *(const short8*)(Ks + r * 64 + ((quad       ^ (r & 7)) * 8));
            short8 ka1 = *(const short8*)(Ks + r * 64 + (((quad + 4) ^ (r & 7)) * 8));
            f32x4 s = {};
            s = __builtin_amdgcn_mfma_f32_16x16x32_bf16(ka0, qb0, s, 0, 0, 0);
            s = __builtin_amdgcn_mfma_f32_16x16x32_bf16(ka1, qb1, s, 0, 0, 0);
            sacc[ft] = s;
        }

        // exp + mask + vectorized P writes (lane: t=myrow, f=ft*16+quad*4+i)
#pragma unroll
        for (int ft = 0; ft < 8; ++ft) {
            const unsigned long long word = (ft < 4) ? w0 : w1;
            const unsigned bits4 =
                (unsigned)(word >> ((ft & 3) * 16 + quad * 4)) & 0xFu;
            union { short4v v; short s[4]; } pk;
            float psum = 0.f;
#pragma unroll
            for (int i = 0; i < 4; ++i) {
                float p = (bits4 >> i) & 1u ? __expf(sacc[ft][i] * 0.125f) : 0.f;
                psum += p;
                pk.s[i] = (short)__bfloat16_as_ushort(__float2bfloat16(p));
            }
            lsum += psum;
            *(short4v*)(Pt + myrow * 136 + ft * 16 + quad * 4) = pk.v;
        }
        w0 = nw0; w1 = nw1;

        // PV A-frags from own Pt rows (in-order same-wave LDS)
        short8 pa[4];
#pragma unroll
        for (int kf = 0; kf < 4; ++kf)
            pa[kf] = *(const short8*)(Pt + myrow * 136 + kf * 32 + quad * 8);
#pragma unroll
        for (int nt = 0; nt < 4; ++nt) {
            int rd = nt * 16 + l16;
#pragma unroll
            for (int kf = 0; kf < 4; ++kf) {
                int g = (kf * 4 + quad) ^ (rd & 15);
                short8 vb = *(const short8*)(Vts + rd * 128 + g * 8);
                oacc[nt] = __builtin_amdgcn_mfma_f32_16x16x32_bf16(pa[kf], vb, oacc[nt], 0, 0, 0);
            }
        }
        __syncthreads();   // protect Ks/Vts before next staging
    }

    // reduce l across quads (lanes sharing l16)
    lsum += __shfl_xor(lsum, 16);
    lsum += __shfl_xor(lsum, 32);
    if (quad == 0) ls[myrow] = lsum;   // same-wave readback below

    // epilogue: normalize (l for t=quad*4+i via ls) + coalesced store via Pt
#pragma unroll
    for (int i = 0; i < 4; ++i) {
        float inv = 1.0f / ls[wave * 16 + quad * 4 + i];
        const int prow = wave * 16 + quad * 4 + i;
#pragma unroll
        for (int nt = 0; nt < 4; ++nt)
            Pt[prow * 136 + nt * 16 + l16] = __float2bfloat16(oacc[nt][i] * inv);
    }
    __syncthreads();
#pragma unroll
    for (int j = 0; j < 2; ++j) {
        int s = j * 256 + tid;
        int rr = s >> 3, off = (s & 7) * 8;
        short8 v = *(const short8*)(Pt + rr * 136 + off);
        *(short8*)(Og + (qrow0 + rr) * DIM + h * HD + off) = v;
    }
}

// ---------------------------------------------------------------------------
extern "C" void kernel_launch(void* const* d_in, const int* in_sizes, int n_in,
                              void* d_out, int out_size, void* d_ws, size_t ws_size,
                              hipStream_t stream) {
    const float* X_to   = (const float*)d_in[0];
    const float* X_from = (const float*)d_in[1];
    const int*   mask   = (const int*)  d_in[2];
    const float* Wq     = (const float*)d_in[3];
    const float* bq     = (const float*)d_in[4];
    const float* Wk     = (const float*)d_in[5];
    const float* bk     = (const float*)d_in[6];
    const float* Wv     = (const float*)d_in[7];
    const float* bv     = (const float*)d_in[8];
    const float* Wo     = (const float*)d_in[9];
    const float* bo     = (const float*)d_in[10];
    float* out = (float*)d_out;

    char* ws = (char*)d_ws;
    bf16* Xt16 = (bf16*)(ws);
    bf16* Xf16 = (bf16*)(ws + (8u  << 20));
    bf16* Wq16 = (bf16*)(ws + (16u << 20));
    bf16* Wv16 = (bf16*)(ws + (18u << 20));
    bf16* Wk16 = (bf16*)(ws + (20u << 20));
    bf16* Wo16 = (bf16*)(ws + (22u << 20));
    bf16* Q16  = (bf16*)(ws + (24u << 20));
    bf16* K16  = (bf16*)(ws + (32u << 20));
    bf16* Vt16 = (bf16*)(ws + (40u << 20));
    unsigned long long* Mb = (unsigned long long*)(ws + (48u << 20));

    ConvArgs ca;
    ca.src[0] = X_to;   ca.dst[0] = Xt16; ca.nvec[0] = MROWS * DIM / 4;
    ca.src[1] = X_from; ca.dst[1] = Xf16; ca.nvec[1] = MROWS * DIM / 4;
    ca.src[2] = Wq;     ca.dst[2] = Wq16; ca.nvec[2] = DIM * DIM / 4;
    ca.src[3] = Wv;     ca.dst[3] = Wv16; ca.nvec[3] = DIM * DIM / 4;
    ca.src[4] = Wk;     ca.dst[4] = Wk16; ca.nvec[4] = DIM * DIM / 4;
    ca.src[5] = Wo;     ca.dst[5] = Wo16; ca.nvec[5] = DIM * DIM / 4;
    int cum = 0;
    for (int k = 0; k < 6; ++k) { cum += ca.nvec[k] / 256; ca.blk_end[k] = cum; }
    ca.mask = mask; ca.Mb = Mb;
    convert_pack<<<cum + 1024, 256, 0, stream>>>(ca);

    QkvArgs qa;
    qa.A[0] = Xt16; qa.W[0] = Wq16; qa.bias[0] = bq; qa.C[0] = Q16;
    qa.N[0] = DIM; qa.biasRow[0] = 0;
    qa.A[1] = Xf16; qa.W[1] = Wv16; qa.bias[1] = bv; qa.C[1] = K16;
    qa.N[1] = DIM; qa.biasRow[1] = 0;
    qa.A[2] = Wk16; qa.W[2] = Xf16; qa.bias[2] = bk; qa.C[2] = Vt16;
    qa.N[2] = MROWS; qa.biasRow[2] = 1;
    gemm_qkv<<<dim3(64, 3), 512, 0, stream>>>(qa);

    attn_kernel<<<dim3(TT / 64, NH, BB), 256, 0, stream>>>(
        Q16, K16, Vt16, Mb, Q16);

    gemm_o<<<dim3(DIM / 64, MROWS / 128), 256, 0, stream>>>(Q16, Wo16, bo, out);
}